// Round 18
// baseline (108.110 us; speedup 1.0000x reference)
//
#include <hip/hip_runtime.h>
#include <math.h>

#define BB    2
#define NN    1024
#define CSD   384
#define CZD   128
#define CHD   16
#define HH    12
#define PQD   4
#define PVD   8
#define KNB   50
#define HALFN 512
#define MTOK  (BB*NN)
#define LINW  1152
#define CATW  2112
#define OSK   6       // split-K for bf16 out-GEMM
#define OKSTEP (CATW / OSK)   // 352 = 11*32
#define ZW    68      // packed zn/Wb row stride in u32 (64 + 4 pad: bank spread)

typedef __attribute__((ext_vector_type(8))) short    bf16x8;
typedef __attribute__((ext_vector_type(4))) float    f32x4;
typedef __attribute__((ext_vector_type(4))) unsigned short us4;

// fp32 -> bf16 round-to-nearest-even (finite inputs; no header dependency)
static __device__ __forceinline__ unsigned short f2b(float x) {
    unsigned u = __float_as_uint(x);
    unsigned rnd = 0x7fffu + ((u >> 16) & 1u);
    return (unsigned short)((u + rnd) >> 16);
}
// unpack 2 bf16 packed in a u32 (lo = even element)
static __device__ __forceinline__ float b2f_lo(unsigned u) { return __uint_as_float(u << 16); }
static __device__ __forceinline__ float b2f_hi(unsigned u) { return __uint_as_float(u & 0xFFFF0000u); }
static __device__ __forceinline__ unsigned pk2(float a, float b) {
    return (unsigned)f2b(a) | ((unsigned)f2b(b) << 16);
}

// ------------- one-pass fp32 -> bf16 conversions: s, packed proj W, Wout -------------
#define CV_N0 (MTOK * CSD / 4)        // s
#define CV_N1 (LINW * CSD / 4)        // packed proj weights
#define CV_N2 (384 * CATW / 4)        // Wout
__global__ __launch_bounds__(256) void convert_all(
    const float* __restrict__ s,
    const float* __restrict__ Wq,  const float* __restrict__ Wkv,
    const float* __restrict__ Wqp, const float* __restrict__ Wkvp,
    const float* __restrict__ Wout,
    unsigned short* __restrict__ sb,
    unsigned short* __restrict__ wpb,
    unsigned short* __restrict__ wob)
{
    const int i4 = blockIdx.x * 256 + threadIdx.x;
    if (i4 < CV_N0) {
        float4 v = *(const float4*)(s + (size_t)i4 * 4);
        us4 o = { f2b(v.x), f2b(v.y), f2b(v.z), f2b(v.w) };
        *(us4*)(sb + (size_t)i4 * 4) = o;
    } else if (i4 < CV_N0 + CV_N1) {
        int j4 = i4 - CV_N0;
        int r = j4 / (CSD / 4), c4 = j4 % (CSD / 4);
        const float* W; int wr;
        if      (r < 192) { W = Wq;   wr = r;       }
        else if (r < 576) { W = Wkv;  wr = r - 192; }
        else if (r < 720) { W = Wqp;  wr = r - 576; }
        else              { W = Wkvp; wr = r - 720; }
        float4 v = *(const float4*)(W + (size_t)wr * CSD + c4 * 4);
        us4 o = { f2b(v.x), f2b(v.y), f2b(v.z), f2b(v.w) };
        *(us4*)(wpb + (size_t)r * CSD + c4 * 4) = o;
    } else if (i4 < CV_N0 + CV_N1 + CV_N2) {
        int j4 = i4 - CV_N0 - CV_N1;
        float4 v = *(const float4*)(Wout + (size_t)j4 * 4);
        us4 o = { f2b(v.x), f2b(v.y), f2b(v.z), f2b(v.w) };
        *(us4*)(wob + (size_t)j4 * 4) = o;
    }
}

// ------------- bf16 MFMA projection GEMM: lin = sb @ wpb^T + bias (f32 out) -------------
__global__ __launch_bounds__(256) void gemm_proj_mfma(
    const unsigned short* __restrict__ sb,     // (2048, 384) bf16
    const unsigned short* __restrict__ wpb,    // (1152, 384) bf16
    const float* __restrict__ bq,  const float* __restrict__ bkv,
    const float* __restrict__ bqp, const float* __restrict__ bkvp,
    float* __restrict__ lin)                   // (2048, 1152) f32
{
    __shared__ unsigned short As[128][40];
    __shared__ unsigned short Bs[64][40];
    const int tid = threadIdx.x;
    const int lane = tid & 63, wv = tid >> 6;
    const int wr = wv >> 1, wc = wv & 1;
    const int rowBase = blockIdx.x * 128;
    const int colBase = blockIdx.y * 64;
    const int sr = tid >> 2;
    const int sq = (tid & 3) * 8;
    const unsigned short* aRow0 = sb  + (size_t)(rowBase + sr) * CSD + sq;
    const unsigned short* aRow1 = sb  + (size_t)(rowBase + 64 + sr) * CSD + sq;
    const unsigned short* bRow  = wpb + (size_t)(colBase + sr) * CSD + sq;

    f32x4 acc[4][2];
    #pragma unroll
    for (int i = 0; i < 4; ++i)
        #pragma unroll
        for (int j = 0; j < 2; ++j)
            acc[i][j] = (f32x4){0.f, 0.f, 0.f, 0.f};

    const int kg = (lane >> 4) * 8;
    const int rr = lane & 15;

    for (int k0 = 0; k0 < CSD; k0 += 32) {
        bf16x8 a0 = *(const bf16x8*)(aRow0 + k0);
        bf16x8 a1 = *(const bf16x8*)(aRow1 + k0);
        bf16x8 b0 = *(const bf16x8*)(bRow  + k0);
        __syncthreads();
        *(bf16x8*)&As[sr][sq]      = a0;
        *(bf16x8*)&As[64 + sr][sq] = a1;
        *(bf16x8*)&Bs[sr][sq]      = b0;
        __syncthreads();
        bf16x8 bfr[2], afr[4];
        #pragma unroll
        for (int fc = 0; fc < 2; ++fc)
            bfr[fc] = *(const bf16x8*)&Bs[wc*32 + fc*16 + rr][kg];
        #pragma unroll
        for (int fr = 0; fr < 4; ++fr)
            afr[fr] = *(const bf16x8*)&As[wr*64 + fr*16 + rr][kg];
        #pragma unroll
        for (int fr = 0; fr < 4; ++fr)
            #pragma unroll
            for (int fc = 0; fc < 2; ++fc)
                acc[fr][fc] = __builtin_amdgcn_mfma_f32_16x16x32_bf16(
                    afr[fr], bfr[fc], acc[fr][fc], 0, 0, 0);
    }

    const int cRowL = (lane >> 4) * 4;
    const int cColL = lane & 15;
    #pragma unroll
    for (int fc = 0; fc < 2; ++fc) {
        int col = colBase + wc*32 + fc*16 + cColL;
        float bia;
        if      (col < 192) bia = bq[col];
        else if (col < 576) bia = bkv[col - 192];
        else if (col < 720) bia = bqp[col - 576];
        else                bia = bkvp[col - 720];
        #pragma unroll
        for (int fr = 0; fr < 4; ++fr) {
            int row0 = rowBase + wr*64 + fr*16 + cRowL;
            #pragma unroll
            for (int g = 0; g < 4; ++g)
                lin[(size_t)(row0 + g) * LINW + col] = acc[fr][fc][g] + bia;
        }
    }
}

// ------------- bf16 MFMA out-GEMM: 128x128 tile (A re-read 6x -> 3x) -------------
// 4 waves (2x2), each wave 64x64 via 4x4 fragments of 16x16x32.
__global__ __launch_bounds__(256) void gemm_out_mfma(
    const unsigned short* __restrict__ catb,   // (2048, 2112) bf16
    const unsigned short* __restrict__ wob,    // (384, 2112) bf16
    float* __restrict__ parts)
{
    __shared__ unsigned short As[128][40];
    __shared__ unsigned short Bs[128][40];
    const int tid = threadIdx.x;
    const int lane = tid & 63, wv = tid >> 6;
    const int wr = wv >> 1, wc = wv & 1;
    const int rowBase = blockIdx.x * 128;
    const int colBase = blockIdx.y * 128;
    const int k0s = blockIdx.z * OKSTEP;
    const int sr = tid >> 2;                 // 0..63
    const int sq = (tid & 3) * 8;            // k offset (bf16)
    const unsigned short* aRow0 = catb + (size_t)(rowBase + sr) * CATW + k0s + sq;
    const unsigned short* aRow1 = catb + (size_t)(rowBase + 64 + sr) * CATW + k0s + sq;
    const unsigned short* bRow0 = wob  + (size_t)(colBase + sr) * CATW + k0s + sq;
    const unsigned short* bRow1 = wob  + (size_t)(colBase + 64 + sr) * CATW + k0s + sq;

    f32x4 acc[4][4];
    #pragma unroll
    for (int i = 0; i < 4; ++i)
        #pragma unroll
        for (int j = 0; j < 4; ++j)
            acc[i][j] = (f32x4){0.f, 0.f, 0.f, 0.f};

    const int kg = (lane >> 4) * 8;
    const int rr = lane & 15;

    for (int k0 = 0; k0 < OKSTEP; k0 += 32) {
        bf16x8 a0 = *(const bf16x8*)(aRow0 + k0);
        bf16x8 a1 = *(const bf16x8*)(aRow1 + k0);
        bf16x8 b0 = *(const bf16x8*)(bRow0 + k0);
        bf16x8 b1 = *(const bf16x8*)(bRow1 + k0);
        __syncthreads();
        *(bf16x8*)&As[sr][sq]      = a0;
        *(bf16x8*)&As[64 + sr][sq] = a1;
        *(bf16x8*)&Bs[sr][sq]      = b0;
        *(bf16x8*)&Bs[64 + sr][sq] = b1;
        __syncthreads();
        bf16x8 bfr[4], afr[4];
        #pragma unroll
        for (int fc = 0; fc < 4; ++fc)
            bfr[fc] = *(const bf16x8*)&Bs[wc*64 + fc*16 + rr][kg];
        #pragma unroll
        for (int fr = 0; fr < 4; ++fr)
            afr[fr] = *(const bf16x8*)&As[wr*64 + fr*16 + rr][kg];
        #pragma unroll
        for (int fr = 0; fr < 4; ++fr)
            #pragma unroll
            for (int fc = 0; fc < 4; ++fc)
                acc[fr][fc] = __builtin_amdgcn_mfma_f32_16x16x32_bf16(
                    afr[fr], bfr[fc], acc[fr][fc], 0, 0, 0);
    }

    float* dst = parts + (size_t)blockIdx.z * MTOK * 384;
    const int cRowL = (lane >> 4) * 4;
    const int cColL = lane & 15;
    #pragma unroll
    for (int fr = 0; fr < 4; ++fr) {
        #pragma unroll
        for (int fc = 0; fc < 4; ++fc) {
            int col = colBase + wc*64 + fc*16 + cColL;
            int row0 = rowBase + wr*64 + fr*16 + cRowL;
            #pragma unroll
            for (int g = 0; g < 4; ++g)
                dst[(size_t)(row0 + g) * 384 + col] = acc[fr][fc][g];
        }
    }
}

__global__ __launch_bounds__(256) void reduce_splitk(
    const float* __restrict__ parts, const float* __restrict__ bias,
    float* __restrict__ out)
{
    const int i4 = blockIdx.x * 256 + threadIdx.x;   // float4 index
    const int TOT4 = MTOK * 384 / 4;
    if (i4 >= TOT4) return;
    const int c4 = i4 % (384 / 4);
    float4 acc = *(const float4*)(bias + c4 * 4);
    #pragma unroll
    for (int s = 0; s < OSK; ++s) {
        float4 p = *(const float4*)(parts + (size_t)s * MTOK * 384 + (size_t)i4 * 4);
        acc.x += p.x; acc.y += p.y; acc.z += p.z; acc.w += p.w;
    }
    *(float4*)(out + (size_t)i4 * 4) = acc;
}

// ------------- point transform: rot @ p + trans -------------
__global__ void point_transform(const float* __restrict__ lin,
                                const float* __restrict__ rot,
                                const float* __restrict__ trans,
                                float* __restrict__ q_pts,
                                float* __restrict__ k_pts,
                                float* __restrict__ v_pts)
{
    const int m = blockIdx.x;
    const int j = threadIdx.x;   // 0..191
    const float* R = rot + (size_t)m * 9;
    const float* T = trans + (size_t)m * 3;
    const float* L = lin + (size_t)m * LINW;
    float p0, p1, p2;
    if (j < 48) {
        p0 = L[576 + j]; p1 = L[576 + 48 + j]; p2 = L[576 + 96 + j];
    } else {
        int j2 = j - 48;                     // 0..143
        p0 = L[720 + j2]; p1 = L[720 + 144 + j2]; p2 = L[720 + 288 + j2];
    }
    float ox = R[0]*p0 + R[1]*p1 + R[2]*p2 + T[0];
    float oy = R[3]*p0 + R[4]*p1 + R[5]*p2 + T[1];
    float oz = R[6]*p0 + R[7]*p1 + R[8]*p2 + T[2];
    if (j < 48) {
        float* o = q_pts + (size_t)m * 144 + 3 * j;
        o[0] = ox; o[1] = oy; o[2] = oz;
    } else {
        int j2 = j - 48, h = j2 / 12, pp = j2 % 12;
        if (pp < PQD) {
            float* o = k_pts + (size_t)m * 144 + ((h*PQD + pp) * 3);
            o[0] = ox; o[1] = oy; o[2] = oz;
        } else {
            float* o = v_pts + (size_t)m * 288 + ((h*PVD + pp - PQD) * 3);
            o[0] = ox; o[1] = oy; o[2] = oz;
        }
    }
}

// ------------- fused top-K + attention per token (round-17 passing version) -------------
__global__ __launch_bounds__(256) void attn_topk_kernel(
    const float* __restrict__ lin,     // q at +0, kv at +192 (per 1152-row)
    const float* __restrict__ q_pts,
    const float* __restrict__ k_pts,
    const float* __restrict__ v_pts,
    const float* __restrict__ trans,
    const float* __restrict__ z,       // (B, 512, 512, 128)
    const float* __restrict__ Wb,      // (12, 128)
    const float* __restrict__ bbv,     // (12)
    const float* __restrict__ hwin,    // (12)
    const float* __restrict__ mask,    // (B, N)
    const float* __restrict__ rot,
    unsigned short* __restrict__ cat)  // (M, 2112) bf16
{
    union TopZ {
        struct {
            float t3[3 * NN];                  // 12288 B
            unsigned int hist[4][256];         //  4096 B
        } t;                                   // 16384 B
        unsigned znb[KNB][ZW];                 // 13600 B (bf16 pairs)
    };
    __shared__ __align__(16) union TopZ u;
    __shared__ __align__(16) unsigned Wbb[HH][ZW];   // 3264 B (bf16 pairs)
    __shared__ float aP[HH][KNB + 2];
    __shared__ __align__(16) float qloc[192];
    __shared__ __align__(16) float qp[144];
    __shared__ int   nk[KNB];
    __shared__ float maskn[KNB];
    __shared__ float hwS[HH];
    __shared__ __align__(16) float opt[288];
    __shared__ unsigned int warp_sums[4];
    __shared__ unsigned int s_seldig, s_selexc, s_selcnt, out_cnt;
    __shared__ unsigned long long s_pivot;
    __shared__ int s_done;

    const int m = blockIdx.x;
    const int b = m / NN, n = m % NN;
    const int tid = threadIdx.x;
    const int lane = tid & 63, wid = tid >> 6;

    // independent loads (overlap with topk phase; separate LDS from union)
    for (int i = tid; i < HH * 64; i += 256) {
        int h = i >> 6, cp = i & 63;
        Wbb[h][cp] = pk2(Wb[h * CZD + cp * 2], Wb[h * CZD + cp * 2 + 1]);
    }
    for (int i = tid; i < 192; i += 256) qloc[i] = lin[(size_t)m * LINW + i];
    for (int i = tid; i < 144; i += 256) qp[i] = q_pts[(size_t)m * 144 + i];
    if (tid < HH) hwS[tid] = log1pf(expf(hwin[tid])) * 0.13608276348795434f; // sqrt(1/54)

    // ---------- Phase 1: top-K radix select (d^2 keys; set is order-invariant) ----------
    if (tid == 0) { s_done = 0; out_cnt = 0; }
    for (int i = tid; i < 3 * NN; i += 256) u.t.t3[i] = trans[(size_t)b * 3 * NN + i];
    __syncthreads();
    const float tx = u.t.t3[n*3], ty = u.t.t3[n*3+1], tz = u.t.t3[n*3+2];
    // key recompute: FIXED op order (mul, fma, fma) -> bit-exact every call
    #define KEYOF(j, kvar) {                                                     \
        float dx_ = tx - u.t.t3[(j)*3], dy_ = ty - u.t.t3[(j)*3+1],              \
              dz_ = tz - u.t.t3[(j)*3+2];                                        \
        float d_ = __fmaf_rn(dz_, dz_, __fmaf_rn(dy_, dy_, dx_*dx_));            \
        kvar = ((unsigned long long)__float_as_uint(d_) << 32) | (unsigned)(j); }
    {
        unsigned long long hi = 0;
        int rank = 0;
        const int target = KNB - 1;
        for (int d = 7; d >= 0; --d) {
            __syncthreads();
            if (s_done) break;
            const int shift = d * 8;
            for (int i = tid; i < 1024; i += 256) ((unsigned int*)u.t.hist)[i] = 0;
            __syncthreads();
            for (int j = tid; j < NN; j += 256) {
                unsigned long long key; KEYOF(j, key);
                bool match = (d == 7) || ((key >> (shift + 8)) == hi);
                if (match) atomicAdd(&u.t.hist[wid][(unsigned)(key >> shift) & 0xffu], 1u);
            }
            __syncthreads();
            unsigned int v = u.t.hist[0][tid] + u.t.hist[1][tid]
                           + u.t.hist[2][tid] + u.t.hist[3][tid];
            unsigned int inc = v;
            #pragma unroll
            for (int off = 1; off < 64; off <<= 1) {
                unsigned int nv = __shfl_up(inc, off);
                if (lane >= off) inc += nv;
            }
            if (lane == 63) warp_sums[wid] = inc;
            __syncthreads();
            unsigned int woff = 0;
            for (int w = 0; w < wid; ++w) woff += warp_sums[w];
            unsigned int exc = woff + inc - v;
            int t = target - rank;
            if ((int)exc <= t && t < (int)(exc + v)) {
                s_seldig = (unsigned)tid; s_selexc = exc; s_selcnt = v;
            }
            __syncthreads();
            hi = (hi << 8) | (unsigned long long)s_seldig;
            rank += (int)s_selexc;
            if (s_selcnt == 1u) {
                for (int j = tid; j < NN; j += 256) {
                    unsigned long long key; KEYOF(j, key);
                    if ((key >> shift) == hi) s_pivot = key;
                }
                if (tid == 0) s_done = 1;
            } else if (d == 0) {
                if (tid == 0) { s_pivot = hi; s_done = 1; }
            }
        }
        __syncthreads();
        const unsigned long long pivot = s_pivot;
        for (int j = tid; j < NN; j += 256) {
            unsigned long long key; KEYOF(j, key);
            if (key <= pivot) {
                unsigned p = atomicAdd(&out_cnt, 1u);
                nk[p] = (int)(key & 0xffffffffu);
            }
        }
    }
    #undef KEYOF
    __syncthreads();   // nk complete; topk scratch dead -> znb may overwrite union

    // ---------- Phase 2: attention ----------
    if (tid < KNB) maskn[tid] = 100000.0f * (mask[m] * mask[(size_t)b * NN + nk[tid]] - 1.0f);
    {
        // z gather: f32 global reads, bf16-pack into LDS (2 u32 per float4)
        const int sub = lane >> 5, l32 = lane & 31;
        for (int k = wid * 2 + sub; k < KNB; k += 8) {
            const float* zr = z + (((size_t)b * HALFN + (n & (HALFN-1))) * HALFN + (nk[k] & (HALFN-1))) * CZD;
            float4 v4 = *(const float4*)(zr + l32 * 4);
            uint2 p;
            p.x = pk2(v4.x, v4.y);
            p.y = pk2(v4.z, v4.w);
            *(uint2*)&u.znb[k][l32 * 2] = p;
        }
    }
    __syncthreads();

    // logits
    for (int idx = tid; idx < HH * KNB; idx += 256) {
        int k = idx / HH, h = idx % HH;
        int mk = b * NN + nk[k];
        const float* kvr = lin + (size_t)mk * LINW + 192 + h * 32;
        float qk = 0.f;
        #pragma unroll
        for (int c4 = 0; c4 < 4; ++c4) {
            float4 kv4 = *(const float4*)(kvr + c4 * 4);
            float4 q4  = *(const float4*)&qloc[h * 16 + c4 * 4];
            qk += q4.x*kv4.x + q4.y*kv4.y + q4.z*kv4.z + q4.w*kv4.w;
        }
        const float* kpr = k_pts + (size_t)mk * 144 + h * 12;
        float kp[12], qv[12];
        *(float4*)&kp[0] = *(const float4*)(kpr);
        *(float4*)&kp[4] = *(const float4*)(kpr + 4);
        *(float4*)&kp[8] = *(const float4*)(kpr + 8);
        *(float4*)&qv[0] = *(const float4*)&qp[h*12];
        *(float4*)&qv[4] = *(const float4*)&qp[h*12 + 4];
        *(float4*)&qv[8] = *(const float4*)&qp[h*12 + 8];
        float d2s = 0.f;
        #pragma unroll
        for (int e = 0; e < 12; ++e) { float dd = qv[e] - kp[e]; d2s += dd*dd; }
        // z·Wb dot from bf16-packed LDS
        float a0 = 0.f, a1 = 0.f, a2 = 0.f, a3 = 0.f;
        #pragma unroll 4
        for (int cp4 = 0; cp4 < 16; ++cp4) {
            uint4 zu = *(const uint4*)&u.znb[k][cp4 * 4];
            uint4 wu = *(const uint4*)&Wbb[h][cp4 * 4];
            a0 += b2f_lo(zu.x)*b2f_lo(wu.x) + b2f_hi(zu.x)*b2f_hi(wu.x);
            a1 += b2f_lo(zu.y)*b2f_lo(wu.y) + b2f_hi(zu.y)*b2f_hi(wu.y);
            a2 += b2f_lo(zu.z)*b2f_lo(wu.z) + b2f_hi(zu.z)*b2f_hi(wu.z);
            a3 += b2f_lo(zu.w)*b2f_lo(wu.w) + b2f_hi(zu.w)*b2f_hi(wu.w);
        }
        float bp = bbv[h] + a0 + a1 + a2 + a3;
        aP[h][k] = qk * 0.14433756729740643f      // sqrt(1/(3*16))
                 + 0.5773502691896258f * bp       // sqrt(1/3)
                 - 0.5f * hwS[h] * d2s
                 + maskn[k];
    }
    __syncthreads();

    // softmax over k per head (wave-parallel, lanes 0..49 hold values)
    for (int h = wid; h < HH; h += 4) {
        float v = (lane < KNB) ? aP[h][lane] : -1e30f;
        float mx = v;
        #pragma unroll
        for (int off = 32; off; off >>= 1) mx = fmaxf(mx, __shfl_xor(mx, off));
        float e = (lane < KNB) ? expf(v - mx) : 0.f;
        float s = e;
        #pragma unroll
        for (int off = 32; off; off >>= 1) s += __shfl_xor(s, off);
        if (lane < KNB) aP[h][lane] = e / s;
    }
    __syncthreads();

    // o (48 float4) and o_pt raw (72 float4) — f32 gathers
    if (tid < 120) {
        float4 acc = {0.f, 0.f, 0.f, 0.f};
        if (tid < 48) {
            int h = tid >> 2, c4 = tid & 3;
            for (int k = 0; k < KNB; ++k) {
                int mk = b * NN + nk[k];
                float4 v4 = *(const float4*)(lin + (size_t)mk * LINW + 192 + h*32 + 16 + c4*4);
                float a = aP[h][k];
                acc.x += a*v4.x; acc.y += a*v4.y; acc.z += a*v4.z; acc.w += a*v4.w;
            }
            us4 o = { f2b(acc.x), f2b(acc.y), f2b(acc.z), f2b(acc.w) };
            *(us4*)(cat + (size_t)m * CATW + tid * 4) = o;
        } else {
            int u2 = tid - 48;                   // 0..71
            int h = (u2 * 4) / 24, r = (u2 * 4) % 24;
            for (int k = 0; k < KNB; ++k) {
                int mk = b * NN + nk[k];
                float4 v4 = *(const float4*)(v_pts + (size_t)mk * 288 + h*24 + r);
                float a = aP[h][k];
                acc.x += a*v4.x; acc.y += a*v4.y; acc.z += a*v4.z; acc.w += a*v4.w;
            }
            *(float4*)&opt[u2 * 4] = acc;
        }
    }

    // o_pair: 192 threads, (hp, c4p); heads hp & hp+6 share each b64 zn read
    if (tid < 192) {
        int hp = tid >> 5, c4p = tid & 31;   // hp 0..5; c4p covers 4 elems (2 u32)
        float ac0[4] = {0.f, 0.f, 0.f, 0.f};
        float ac1[4] = {0.f, 0.f, 0.f, 0.f};
        for (int k = 0; k < KNB; ++k) {
            float a0 = aP[hp][k], a1 = aP[hp + 6][k];
            uint2 zu = *(const uint2*)&u.znb[k][c4p * 2];
            float e0 = b2f_lo(zu.x), e1 = b2f_hi(zu.x);
            float e2 = b2f_lo(zu.y), e3 = b2f_hi(zu.y);
            ac0[0] += a0*e0; ac0[1] += a0*e1; ac0[2] += a0*e2; ac0[3] += a0*e3;
            ac1[0] += a1*e0; ac1[1] += a1*e1; ac1[2] += a1*e2; ac1[3] += a1*e3;
        }
        us4 o0 = { f2b(ac0[0]), f2b(ac0[1]), f2b(ac0[2]), f2b(ac0[3]) };
        us4 o1 = { f2b(ac1[0]), f2b(ac1[1]), f2b(ac1[2]), f2b(ac1[3]) };
        *(us4*)(cat + (size_t)m * CATW + 576 + hp * 128 + c4p * 4) = o0;
        *(us4*)(cat + (size_t)m * CATW + 576 + (hp + 6) * 128 + c4p * 4) = o1;
    }
    __syncthreads();

    // inverse frame transform + norm
    if (tid < 96) {
        int hp = tid;
        float x = opt[hp*3+0] - trans[(size_t)m*3+0];
        float y = opt[hp*3+1] - trans[(size_t)m*3+1];
        float z0 = opt[hp*3+2] - trans[(size_t)m*3+2];
        const float* R = rot + (size_t)m * 9;
        float o0 = R[0]*x + R[3]*y + R[6]*z0;   // rot^T
        float o1 = R[1]*x + R[4]*y + R[7]*z0;
        float o2 = R[2]*x + R[5]*y + R[8]*z0;
        float nrm = sqrtf(o0*o0 + o1*o1 + o2*o2 + 1e-8f);
        unsigned short* c0 = cat + (size_t)m * CATW;
        c0[192 + hp] = f2b(o0);
        c0[288 + hp] = f2b(o1);
        c0[384 + hp] = f2b(o2);
        c0[480 + hp] = f2b(nrm);
    }
}

extern "C" void kernel_launch(void* const* d_in, const int* in_sizes, int n_in,
                              void* d_out, int out_size, void* d_ws, size_t ws_size,
                              hipStream_t stream) {
    const float* s     = (const float*)d_in[0];
    const float* z     = (const float*)d_in[1];
    const float* rot   = (const float*)d_in[2];
    const float* trans = (const float*)d_in[3];
    const float* mask  = (const float*)d_in[4];
    // d_in[5] rel_pos unused
    const float* Wq    = (const float*)d_in[6];
    const float* bq    = (const float*)d_in[7];
    const float* Wkv   = (const float*)d_in[8];
    const float* bkv   = (const float*)d_in[9];
    const float* Wqp   = (const float*)d_in[10];
    const float* bqp   = (const float*)d_in[11];
    const float* Wkvp  = (const float*)d_in[12];
    const float* bkvp  = (const float*)d_in[13];
    const float* Wb    = (const float*)d_in[14];
    const float* bb    = (const float*)d_in[15];
    const float* hw    = (const float*)d_in[16];
    const float* Wout  = (const float*)d_in[17];
    const float* bout  = (const float*)d_in[18];
    float* out = (float*)d_out;

    float* ws    = (float*)d_ws;
    float* lin   = ws;                              // 2048*1152 f32
    float* qpts  = lin  + (size_t)MTOK * LINW;      // 2048*144 f32
    float* kpts  = qpts + (size_t)MTOK * 144;       // 2048*144 f32
    float* vpts  = kpts + (size_t)MTOK * 144;       // 2048*288 f32
    unsigned short* catb = (unsigned short*)(vpts + (size_t)MTOK * 288);  // 2048*2112 bf16
    unsigned short* wob  = catb + (size_t)MTOK * CATW;                    // 384*2112 bf16
    unsigned short* sb   = wob  + (size_t)384 * CATW;                     // 2048*384 bf16
    unsigned short* wpb  = sb   + (size_t)MTOK * CSD;                     // 1152*384 bf16
    float* parts = (float*)(wpb + (size_t)LINW * CSD);                    // OSK*2048*384 f32

    const int CV_TOT = CV_N0 + CV_N1 + CV_N2;
    convert_all<<<(CV_TOT + 255) / 256, 256, 0, stream>>>(s, Wq, Wkv, Wqp, Wkvp, Wout,
                                                          sb, wpb, wob);
    dim3 g1(MTOK / 128, LINW / 64);
    gemm_proj_mfma<<<g1, 256, 0, stream>>>(sb, wpb, bq, bkv, bqp, bkvp, lin);
    point_transform<<<MTOK, 192, 0, stream>>>(lin, rot, trans, qpts, kpts, vpts);
    attn_topk_kernel<<<MTOK, 256, 0, stream>>>(lin, qpts, kpts, vpts, trans, z,
                                               Wb, bb, hw, mask, rot, catb);
    dim3 g2(MTOK / 128, 384 / 128, OSK);
    gemm_out_mfma<<<g2, 256, 0, stream>>>(catb, wob, parts);
    reduce_splitk<<<(MTOK * 384 / 4 + 255) / 256, 256, 0, stream>>>(parts, bout, out);
}

// Round 19
// 105.114 us; speedup vs baseline: 1.0285x; 1.0285x over previous
//
#include <hip/hip_runtime.h>
#include <math.h>

#define BB    2
#define NN    1024
#define CSD   384
#define CZD   128
#define CZP   132     // padded LDS row (bank spread)
#define CHD   16
#define HH    12
#define PQD   4
#define PVD   8
#define KNB   50
#define HALFN 512
#define MTOK  (BB*NN)
#define LINW  1152
#define CATW  2112
#define OSK   6       // split-K for bf16 out-GEMM
#define OKSTEP (CATW / OSK)   // 352 = 11*32

typedef __attribute__((ext_vector_type(8))) short    bf16x8;
typedef __attribute__((ext_vector_type(4))) float    f32x4;
typedef __attribute__((ext_vector_type(4))) unsigned short us4;

// fp32 -> bf16 round-to-nearest-even (finite inputs; no header dependency)
static __device__ __forceinline__ unsigned short f2b(float x) {
    unsigned u = __float_as_uint(x);
    unsigned rnd = 0x7fffu + ((u >> 16) & 1u);
    return (unsigned short)((u + rnd) >> 16);
}

// ------------- one-pass fp32 -> bf16 conversions: s, packed proj W, Wout -------------
#define CV_N0 (MTOK * CSD / 4)        // s
#define CV_N1 (LINW * CSD / 4)        // packed proj weights
#define CV_N2 (384 * CATW / 4)        // Wout
__global__ __launch_bounds__(256) void convert_all(
    const float* __restrict__ s,
    const float* __restrict__ Wq,  const float* __restrict__ Wkv,
    const float* __restrict__ Wqp, const float* __restrict__ Wkvp,
    const float* __restrict__ Wout,
    unsigned short* __restrict__ sb,
    unsigned short* __restrict__ wpb,
    unsigned short* __restrict__ wob)
{
    const int i4 = blockIdx.x * 256 + threadIdx.x;
    if (i4 < CV_N0) {
        float4 v = *(const float4*)(s + (size_t)i4 * 4);
        us4 o = { f2b(v.x), f2b(v.y), f2b(v.z), f2b(v.w) };
        *(us4*)(sb + (size_t)i4 * 4) = o;
    } else if (i4 < CV_N0 + CV_N1) {
        int j4 = i4 - CV_N0;
        int r = j4 / (CSD / 4), c4 = j4 % (CSD / 4);
        const float* W; int wr;
        if      (r < 192) { W = Wq;   wr = r;       }
        else if (r < 576) { W = Wkv;  wr = r - 192; }
        else if (r < 720) { W = Wqp;  wr = r - 576; }
        else              { W = Wkvp; wr = r - 720; }
        float4 v = *(const float4*)(W + (size_t)wr * CSD + c4 * 4);
        us4 o = { f2b(v.x), f2b(v.y), f2b(v.z), f2b(v.w) };
        *(us4*)(wpb + (size_t)r * CSD + c4 * 4) = o;
    } else if (i4 < CV_N0 + CV_N1 + CV_N2) {
        int j4 = i4 - CV_N0 - CV_N1;
        float4 v = *(const float4*)(Wout + (size_t)j4 * 4);
        us4 o = { f2b(v.x), f2b(v.y), f2b(v.z), f2b(v.w) };
        *(us4*)(wob + (size_t)j4 * 4) = o;
    }
}

// ------------- bf16 MFMA projection GEMM: lin = sb @ wpb^T + bias (f32 out) -------------
__global__ __launch_bounds__(256) void gemm_proj_mfma(
    const unsigned short* __restrict__ sb,     // (2048, 384) bf16
    const unsigned short* __restrict__ wpb,    // (1152, 384) bf16
    const float* __restrict__ bq,  const float* __restrict__ bkv,
    const float* __restrict__ bqp, const float* __restrict__ bkvp,
    float* __restrict__ lin)                   // (2048, 1152) f32
{
    __shared__ unsigned short As[128][40];
    __shared__ unsigned short Bs[64][40];
    const int tid = threadIdx.x;
    const int lane = tid & 63, wv = tid >> 6;
    const int wr = wv >> 1, wc = wv & 1;
    const int rowBase = blockIdx.x * 128;
    const int colBase = blockIdx.y * 64;
    const int sr = tid >> 2;
    const int sq = (tid & 3) * 8;
    const unsigned short* aRow0 = sb  + (size_t)(rowBase + sr) * CSD + sq;
    const unsigned short* aRow1 = sb  + (size_t)(rowBase + 64 + sr) * CSD + sq;
    const unsigned short* bRow  = wpb + (size_t)(colBase + sr) * CSD + sq;

    f32x4 acc[4][2];
    #pragma unroll
    for (int i = 0; i < 4; ++i)
        #pragma unroll
        for (int j = 0; j < 2; ++j)
            acc[i][j] = (f32x4){0.f, 0.f, 0.f, 0.f};

    const int kg = (lane >> 4) * 8;
    const int rr = lane & 15;

    for (int k0 = 0; k0 < CSD; k0 += 32) {
        bf16x8 a0 = *(const bf16x8*)(aRow0 + k0);
        bf16x8 a1 = *(const bf16x8*)(aRow1 + k0);
        bf16x8 b0 = *(const bf16x8*)(bRow  + k0);
        __syncthreads();
        *(bf16x8*)&As[sr][sq]      = a0;
        *(bf16x8*)&As[64 + sr][sq] = a1;
        *(bf16x8*)&Bs[sr][sq]      = b0;
        __syncthreads();
        bf16x8 bfr[2], afr[4];
        #pragma unroll
        for (int fc = 0; fc < 2; ++fc)
            bfr[fc] = *(const bf16x8*)&Bs[wc*32 + fc*16 + rr][kg];
        #pragma unroll
        for (int fr = 0; fr < 4; ++fr)
            afr[fr] = *(const bf16x8*)&As[wr*64 + fr*16 + rr][kg];
        #pragma unroll
        for (int fr = 0; fr < 4; ++fr)
            #pragma unroll
            for (int fc = 0; fc < 2; ++fc)
                acc[fr][fc] = __builtin_amdgcn_mfma_f32_16x16x32_bf16(
                    afr[fr], bfr[fc], acc[fr][fc], 0, 0, 0);
    }

    const int cRowL = (lane >> 4) * 4;
    const int cColL = lane & 15;
    #pragma unroll
    for (int fc = 0; fc < 2; ++fc) {
        int col = colBase + wc*32 + fc*16 + cColL;
        float bia;
        if      (col < 192) bia = bq[col];
        else if (col < 576) bia = bkv[col - 192];
        else if (col < 720) bia = bqp[col - 576];
        else                bia = bkvp[col - 720];
        #pragma unroll
        for (int fr = 0; fr < 4; ++fr) {
            int row0 = rowBase + wr*64 + fr*16 + cRowL;
            #pragma unroll
            for (int g = 0; g < 4; ++g)
                lin[(size_t)(row0 + g) * LINW + col] = acc[fr][fc][g] + bia;
        }
    }
}

// ------------- bf16 MFMA out-GEMM: parts[z] = catb @ wob^T over k-chunk -------------
__global__ __launch_bounds__(256) void gemm_out_mfma(
    const unsigned short* __restrict__ catb,   // (2048, 2112) bf16
    const unsigned short* __restrict__ wob,    // (384, 2112) bf16
    float* __restrict__ parts)
{
    __shared__ unsigned short As[128][40];
    __shared__ unsigned short Bs[64][40];
    const int tid = threadIdx.x;
    const int lane = tid & 63, wv = tid >> 6;
    const int wr = wv >> 1, wc = wv & 1;
    const int rowBase = blockIdx.x * 128;
    const int colBase = blockIdx.y * 64;
    const int k0s = blockIdx.z * OKSTEP;
    const int sr = tid >> 2;
    const int sq = (tid & 3) * 8;
    const unsigned short* aRow0 = catb + (size_t)(rowBase + sr) * CATW + k0s + sq;
    const unsigned short* aRow1 = catb + (size_t)(rowBase + 64 + sr) * CATW + k0s + sq;
    const unsigned short* bRow  = wob  + (size_t)(colBase + sr) * CATW + k0s + sq;

    f32x4 acc[4][2];
    #pragma unroll
    for (int i = 0; i < 4; ++i)
        #pragma unroll
        for (int j = 0; j < 2; ++j)
            acc[i][j] = (f32x4){0.f, 0.f, 0.f, 0.f};

    const int kg = (lane >> 4) * 8;
    const int rr = lane & 15;

    for (int k0 = 0; k0 < OKSTEP; k0 += 32) {
        bf16x8 a0 = *(const bf16x8*)(aRow0 + k0);
        bf16x8 a1 = *(const bf16x8*)(aRow1 + k0);
        bf16x8 b0 = *(const bf16x8*)(bRow  + k0);
        __syncthreads();
        *(bf16x8*)&As[sr][sq]      = a0;
        *(bf16x8*)&As[64 + sr][sq] = a1;
        *(bf16x8*)&Bs[sr][sq]      = b0;
        __syncthreads();
        bf16x8 bfr[2], afr[4];
        #pragma unroll
        for (int fc = 0; fc < 2; ++fc)
            bfr[fc] = *(const bf16x8*)&Bs[wc*32 + fc*16 + rr][kg];
        #pragma unroll
        for (int fr = 0; fr < 4; ++fr)
            afr[fr] = *(const bf16x8*)&As[wr*64 + fr*16 + rr][kg];
        #pragma unroll
        for (int fr = 0; fr < 4; ++fr)
            #pragma unroll
            for (int fc = 0; fc < 2; ++fc)
                acc[fr][fc] = __builtin_amdgcn_mfma_f32_16x16x32_bf16(
                    afr[fr], bfr[fc], acc[fr][fc], 0, 0, 0);
    }

    float* dst = parts + (size_t)blockIdx.z * MTOK * 384;
    const int cRowL = (lane >> 4) * 4;
    const int cColL = lane & 15;
    #pragma unroll
    for (int fr = 0; fr < 4; ++fr) {
        #pragma unroll
        for (int fc = 0; fc < 2; ++fc) {
            int col = colBase + wc*32 + fc*16 + cColL;
            int row0 = rowBase + wr*64 + fr*16 + cRowL;
            #pragma unroll
            for (int g = 0; g < 4; ++g)
                dst[(size_t)(row0 + g) * 384 + col] = acc[fr][fc][g];
        }
    }
}

__global__ __launch_bounds__(256) void reduce_splitk(
    const float* __restrict__ parts, const float* __restrict__ bias,
    float* __restrict__ out)
{
    const int i4 = blockIdx.x * 256 + threadIdx.x;   // float4 index
    const int TOT4 = MTOK * 384 / 4;
    if (i4 >= TOT4) return;
    const int c4 = i4 % (384 / 4);
    float4 acc = *(const float4*)(bias + c4 * 4);
    #pragma unroll
    for (int s = 0; s < OSK; ++s) {
        float4 p = *(const float4*)(parts + (size_t)s * MTOK * 384 + (size_t)i4 * 4);
        acc.x += p.x; acc.y += p.y; acc.z += p.z; acc.w += p.w;
    }
    *(float4*)(out + (size_t)i4 * 4) = acc;
}

// ------------- point transform: rot @ p + trans -------------
__global__ void point_transform(const float* __restrict__ lin,
                                const float* __restrict__ rot,
                                const float* __restrict__ trans,
                                float* __restrict__ q_pts,
                                float* __restrict__ k_pts,
                                float* __restrict__ v_pts)
{
    const int m = blockIdx.x;
    const int j = threadIdx.x;   // 0..191
    const float* R = rot + (size_t)m * 9;
    const float* T = trans + (size_t)m * 3;
    const float* L = lin + (size_t)m * LINW;
    float p0, p1, p2;
    if (j < 48) {
        p0 = L[576 + j]; p1 = L[576 + 48 + j]; p2 = L[576 + 96 + j];
    } else {
        int j2 = j - 48;                     // 0..143
        p0 = L[720 + j2]; p1 = L[720 + 144 + j2]; p2 = L[720 + 288 + j2];
    }
    float ox = R[0]*p0 + R[1]*p1 + R[2]*p2 + T[0];
    float oy = R[3]*p0 + R[4]*p1 + R[5]*p2 + T[1];
    float oz = R[6]*p0 + R[7]*p1 + R[8]*p2 + T[2];
    if (j < 48) {
        float* o = q_pts + (size_t)m * 144 + 3 * j;
        o[0] = ox; o[1] = oy; o[2] = oz;
    } else {
        int j2 = j - 48, h = j2 / 12, pp = j2 % 12;
        if (pp < PQD) {
            float* o = k_pts + (size_t)m * 144 + ((h*PQD + pp) * 3);
            o[0] = ox; o[1] = oy; o[2] = oz;
        } else {
            float* o = v_pts + (size_t)m * 288 + ((h*PVD + pp - PQD) * 3);
            o[0] = ox; o[1] = oy; o[2] = oz;
        }
    }
}

// ------------- fused top-K + attention per token (round-11 best: 104.9 us) -------------
__global__ __launch_bounds__(256) void attn_topk_kernel(
    const float* __restrict__ lin,     // q at +0, kv at +192 (per 1152-row)
    const float* __restrict__ q_pts,
    const float* __restrict__ k_pts,
    const float* __restrict__ v_pts,
    const float* __restrict__ trans,
    const float* __restrict__ z,       // (B, 512, 512, 128)
    const float* __restrict__ Wb,      // (12, 128)
    const float* __restrict__ bbv,     // (12)
    const float* __restrict__ hwin,    // (12)
    const float* __restrict__ mask,    // (B, N)
    const float* __restrict__ rot,
    unsigned short* __restrict__ cat)  // (M, 2112) bf16
{
    union TopZ {
        struct {
            float t3[3 * NN];                  // 12288 B
            unsigned long long keys[NN];       //  8192 B
            unsigned int hist[4][256];         //  4096 B
        } t;
        float zn[KNB][CZP];                    // 26400 B
    };
    __shared__ __align__(16) union TopZ u;
    __shared__ __align__(16) float WbS[HH][CZP];
    __shared__ float aP[HH][KNB + 2];
    __shared__ __align__(16) float qloc[192];
    __shared__ __align__(16) float qp[144];
    __shared__ int   nk[KNB];
    __shared__ float maskn[KNB];
    __shared__ float hwS[HH];
    __shared__ __align__(16) float opt[288];
    __shared__ unsigned int warp_sums[4];
    __shared__ unsigned int s_seldig, s_selexc, s_selcnt, out_cnt;
    __shared__ unsigned long long s_pivot;
    __shared__ int s_done;

    const int m = blockIdx.x;
    const int b = m / NN, n = m % NN;
    const int tid = threadIdx.x;
    const int lane = tid & 63, wid = tid >> 6;

    // independent loads (overlap with topk phase; separate LDS from union)
    for (int i = tid; i < HH * CZD; i += 256) WbS[i / CZD][i % CZD] = Wb[i];
    for (int i = tid; i < 192; i += 256) qloc[i] = lin[(size_t)m * LINW + i];
    for (int i = tid; i < 144; i += 256) qp[i] = q_pts[(size_t)m * 144 + i];
    if (tid < HH) hwS[tid] = log1pf(expf(hwin[tid])) * 0.13608276348795434f; // sqrt(1/54)

    // ---------- Phase 1: top-K radix select (d^2 keys; set is order-invariant) ----------
    if (tid == 0) { s_done = 0; out_cnt = 0; }
    for (int i = tid; i < 3 * NN; i += 256) u.t.t3[i] = trans[(size_t)b * 3 * NN + i];
    __syncthreads();
    {
        const float tx = u.t.t3[n*3], ty = u.t.t3[n*3+1], tz = u.t.t3[n*3+2];
        for (int j = tid; j < NN; j += 256) {
            float dx = tx - u.t.t3[j*3], dy = ty - u.t.t3[j*3+1], dz = tz - u.t.t3[j*3+2];
            float d = dx*dx + dy*dy + dz*dz;
            u.t.keys[j] = ((unsigned long long)__float_as_uint(d) << 32) | (unsigned)j;
        }
    }
    {
        unsigned long long hi = 0;
        int rank = 0;
        const int target = KNB - 1;
        for (int d = 7; d >= 0; --d) {
            __syncthreads();
            if (s_done) break;
            const int shift = d * 8;
            for (int i = tid; i < 1024; i += 256) ((unsigned int*)u.t.hist)[i] = 0;
            __syncthreads();
            for (int j = tid; j < NN; j += 256) {
                unsigned long long key = u.t.keys[j];
                bool match = (d == 7) || ((key >> (shift + 8)) == hi);
                if (match) atomicAdd(&u.t.hist[wid][(unsigned)(key >> shift) & 0xffu], 1u);
            }
            __syncthreads();
            unsigned int v = u.t.hist[0][tid] + u.t.hist[1][tid]
                           + u.t.hist[2][tid] + u.t.hist[3][tid];
            unsigned int inc = v;
            #pragma unroll
            for (int off = 1; off < 64; off <<= 1) {
                unsigned int nv = __shfl_up(inc, off);
                if (lane >= off) inc += nv;
            }
            if (lane == 63) warp_sums[wid] = inc;
            __syncthreads();
            unsigned int woff = 0;
            for (int w = 0; w < wid; ++w) woff += warp_sums[w];
            unsigned int exc = woff + inc - v;
            int t = target - rank;
            if ((int)exc <= t && t < (int)(exc + v)) {
                s_seldig = (unsigned)tid; s_selexc = exc; s_selcnt = v;
            }
            __syncthreads();
            hi = (hi << 8) | (unsigned long long)s_seldig;
            rank += (int)s_selexc;
            if (s_selcnt == 1u) {
                for (int j = tid; j < NN; j += 256) {
                    unsigned long long key = u.t.keys[j];
                    if ((key >> shift) == hi) s_pivot = key;
                }
                if (tid == 0) s_done = 1;
            } else if (d == 0) {
                if (tid == 0) { s_pivot = hi; s_done = 1; }
            }
        }
        __syncthreads();
        const unsigned long long pivot = s_pivot;
        for (int j = tid; j < NN; j += 256) {
            unsigned long long key = u.t.keys[j];
            if (key <= pivot) {
                unsigned p = atomicAdd(&out_cnt, 1u);
                nk[p] = (int)(key & 0xffffffffu);
            }
        }
    }
    __syncthreads();   // nk complete; topk scratch dead -> zn may overwrite union

    // ---------- Phase 2: attention ----------
    if (tid < KNB) maskn[tid] = 100000.0f * (mask[m] * mask[(size_t)b * NN + nk[tid]] - 1.0f);
    {
        const int sub = lane >> 5, l32 = lane & 31;
        for (int k = wid * 2 + sub; k < KNB; k += 8) {
            const float* zr = z + (((size_t)b * HALFN + (n & (HALFN-1))) * HALFN + (nk[k] & (HALFN-1))) * CZD;
            float4 v4 = *(const float4*)(zr + l32 * 4);
            *(float4*)&u.zn[k][l32 * 4] = v4;
        }
    }
    __syncthreads();

    // logits
    for (int idx = tid; idx < HH * KNB; idx += 256) {
        int k = idx / HH, h = idx % HH;
        int mk = b * NN + nk[k];
        const float* kvr = lin + (size_t)mk * LINW + 192 + h * 32;
        float qk = 0.f;
        #pragma unroll
        for (int c4 = 0; c4 < 4; ++c4) {
            float4 kv4 = *(const float4*)(kvr + c4 * 4);
            float4 q4  = *(const float4*)&qloc[h * 16 + c4 * 4];
            qk += q4.x*kv4.x + q4.y*kv4.y + q4.z*kv4.z + q4.w*kv4.w;
        }
        const float* kpr = k_pts + (size_t)mk * 144 + h * 12;
        float kp[12], qv[12];
        *(float4*)&kp[0] = *(const float4*)(kpr);
        *(float4*)&kp[4] = *(const float4*)(kpr + 4);
        *(float4*)&kp[8] = *(const float4*)(kpr + 8);
        *(float4*)&qv[0] = *(const float4*)&qp[h*12];
        *(float4*)&qv[4] = *(const float4*)&qp[h*12 + 4];
        *(float4*)&qv[8] = *(const float4*)&qp[h*12 + 8];
        float d2s = 0.f;
        #pragma unroll
        for (int e = 0; e < 12; ++e) { float dd = qv[e] - kp[e]; d2s += dd*dd; }
        float4 acc4 = {0.f, 0.f, 0.f, 0.f};
        #pragma unroll 8
        for (int c4 = 0; c4 < 32; ++c4) {
            float4 z4 = *(const float4*)&u.zn[k][c4 * 4];
            float4 w4 = *(const float4*)&WbS[h][c4 * 4];
            acc4.x += z4.x*w4.x; acc4.y += z4.y*w4.y;
            acc4.z += z4.z*w4.z; acc4.w += z4.w*w4.w;
        }
        float bp = bbv[h] + acc4.x + acc4.y + acc4.z + acc4.w;
        aP[h][k] = qk * 0.14433756729740643f      // sqrt(1/(3*16))
                 + 0.5773502691896258f * bp       // sqrt(1/3)
                 - 0.5f * hwS[h] * d2s
                 + maskn[k];
    }
    __syncthreads();

    // softmax over k per head (wave-parallel, lanes 0..49 hold values)
    for (int h = wid; h < HH; h += 4) {
        float v = (lane < KNB) ? aP[h][lane] : -1e30f;
        float mx = v;
        #pragma unroll
        for (int off = 32; off; off >>= 1) mx = fmaxf(mx, __shfl_xor(mx, off));
        float e = (lane < KNB) ? expf(v - mx) : 0.f;
        float s = e;
        #pragma unroll
        for (int off = 32; off; off >>= 1) s += __shfl_xor(s, off);
        if (lane < KNB) aP[h][lane] = e / s;
    }
    __syncthreads();

    // o (48 float4) and o_pt raw (72 float4)
    if (tid < 120) {
        float4 acc = {0.f, 0.f, 0.f, 0.f};
        if (tid < 48) {
            int h = tid >> 2, c4 = tid & 3;
            for (int k = 0; k < KNB; ++k) {
                int mk = b * NN + nk[k];
                float4 v4 = *(const float4*)(lin + (size_t)mk * LINW + 192 + h*32 + 16 + c4*4);
                float a = aP[h][k];
                acc.x += a*v4.x; acc.y += a*v4.y; acc.z += a*v4.z; acc.w += a*v4.w;
            }
            us4 o = { f2b(acc.x), f2b(acc.y), f2b(acc.z), f2b(acc.w) };
            *(us4*)(cat + (size_t)m * CATW + tid * 4) = o;
        } else {
            int u2 = tid - 48;                   // 0..71
            int h = (u2 * 4) / 24, r = (u2 * 4) % 24;
            for (int k = 0; k < KNB; ++k) {
                int mk = b * NN + nk[k];
                float4 v4 = *(const float4*)(v_pts + (size_t)mk * 288 + h*24 + r);
                float a = aP[h][k];
                acc.x += a*v4.x; acc.y += a*v4.y; acc.z += a*v4.z; acc.w += a*v4.w;
            }
            *(float4*)&opt[u2 * 4] = acc;
        }
    }

    // o_pair: 2 heads per thread share each zn row read (192 threads: (hp, c4))
    if (tid < 192) {
        int hp = tid >> 5, c4 = tid & 31;    // hp 0..5 -> heads hp, hp+6
        float4 acc0 = {0.f, 0.f, 0.f, 0.f};
        float4 acc1 = {0.f, 0.f, 0.f, 0.f};
        for (int k = 0; k < KNB; ++k) {
            float a0 = aP[hp][k], a1 = aP[hp + 6][k];
            float4 z4 = *(const float4*)&u.zn[k][c4 * 4];
            acc0.x += a0*z4.x; acc0.y += a0*z4.y; acc0.z += a0*z4.z; acc0.w += a0*z4.w;
            acc1.x += a1*z4.x; acc1.y += a1*z4.y; acc1.z += a1*z4.z; acc1.w += a1*z4.w;
        }
        us4 o0 = { f2b(acc0.x), f2b(acc0.y), f2b(acc0.z), f2b(acc0.w) };
        us4 o1 = { f2b(acc1.x), f2b(acc1.y), f2b(acc1.z), f2b(acc1.w) };
        *(us4*)(cat + (size_t)m * CATW + 576 + hp * 128 + c4 * 4) = o0;
        *(us4*)(cat + (size_t)m * CATW + 576 + (hp + 6) * 128 + c4 * 4) = o1;
    }
    __syncthreads();

    // inverse frame transform + norm
    if (tid < 96) {
        int hp = tid;
        float x = opt[hp*3+0] - trans[(size_t)m*3+0];
        float y = opt[hp*3+1] - trans[(size_t)m*3+1];
        float z0 = opt[hp*3+2] - trans[(size_t)m*3+2];
        const float* R = rot + (size_t)m * 9;
        float o0 = R[0]*x + R[3]*y + R[6]*z0;   // rot^T
        float o1 = R[1]*x + R[4]*y + R[7]*z0;
        float o2 = R[2]*x + R[5]*y + R[8]*z0;
        float nrm = sqrtf(o0*o0 + o1*o1 + o2*o2 + 1e-8f);
        unsigned short* c0 = cat + (size_t)m * CATW;
        c0[192 + hp] = f2b(o0);
        c0[288 + hp] = f2b(o1);
        c0[384 + hp] = f2b(o2);
        c0[480 + hp] = f2b(nrm);
    }
}

extern "C" void kernel_launch(void* const* d_in, const int* in_sizes, int n_in,
                              void* d_out, int out_size, void* d_ws, size_t ws_size,
                              hipStream_t stream) {
    const float* s     = (const float*)d_in[0];
    const float* z     = (const float*)d_in[1];
    const float* rot   = (const float*)d_in[2];
    const float* trans = (const float*)d_in[3];
    const float* mask  = (const float*)d_in[4];
    // d_in[5] rel_pos unused
    const float* Wq    = (const float*)d_in[6];
    const float* bq    = (const float*)d_in[7];
    const float* Wkv   = (const float*)d_in[8];
    const float* bkv   = (const float*)d_in[9];
    const float* Wqp   = (const float*)d_in[10];
    const float* bqp   = (const float*)d_in[11];
    const float* Wkvp  = (const float*)d_in[12];
    const float* bkvp  = (const float*)d_in[13];
    const float* Wb    = (const float*)d_in[14];
    const float* bb    = (const float*)d_in[15];
    const float* hw    = (const float*)d_in[16];
    const float* Wout  = (const float*)d_in[17];
    const float* bout  = (const float*)d_in[18];
    float* out = (float*)d_out;

    float* ws    = (float*)d_ws;
    float* lin   = ws;                              // 2048*1152 f32
    float* qpts  = lin  + (size_t)MTOK * LINW;      // 2048*144 f32
    float* kpts  = qpts + (size_t)MTOK * 144;       // 2048*144 f32
    float* vpts  = kpts + (size_t)MTOK * 144;       // 2048*288 f32
    unsigned short* catb = (unsigned short*)(vpts + (size_t)MTOK * 288);  // 2048*2112 bf16
    unsigned short* wob  = catb + (size_t)MTOK * CATW;                    // 384*2112 bf16
    unsigned short* sb   = wob  + (size_t)384 * CATW;                     // 2048*384 bf16
    unsigned short* wpb  = sb   + (size_t)MTOK * CSD;                     // 1152*384 bf16
    float* parts = (float*)(wpb + (size_t)LINW * CSD);                    // OSK*2048*384 f32

    const int CV_TOT = CV_N0 + CV_N1 + CV_N2;
    convert_all<<<(CV_TOT + 255) / 256, 256, 0, stream>>>(s, Wq, Wkv, Wqp, Wkvp, Wout,
                                                          sb, wpb, wob);
    dim3 g1(MTOK / 128, LINW / 64);
    gemm_proj_mfma<<<g1, 256, 0, stream>>>(sb, wpb, bq, bkv, bqp, bkvp, lin);
    point_transform<<<MTOK, 192, 0, stream>>>(lin, rot, trans, qpts, kpts, vpts);
    attn_topk_kernel<<<MTOK, 256, 0, stream>>>(lin, qpts, kpts, vpts, trans, z,
                                               Wb, bb, hw, mask, rot, catb);
    dim3 g2(MTOK / 128, 384 / 64, OSK);
    gemm_out_mfma<<<g2, 256, 0, stream>>>(catb, wob, parts);
    reduce_splitk<<<(MTOK * 384 / 4 + 255) / 256, 256, 0, stream>>>(parts, bout, out);
}